// Round 13
// baseline (593.647 us; speedup 1.0000x reference)
//
#include <hip/hip_runtime.h>
#include <hip/hip_bf16.h>

// STCN read_memory: affinity softmax over THW + value readout.
// Single-S-pass: P~ = exp2(L - Mbound(j)), l~(j) = sum_t P~; out = (sum P~ V)/l~.
#define CKDIM 64
#define THW   12960     // 8*30*54
#define HWDIM 1620      // 30*54
#define NOBJ  8
#define CVAL  512
#define NB    4
#define NSTEP 405       // THW / 32
#define NJT   13        // ceil(1620/128)
#define PCH   16        // P-write K-chunks
#define S2F   0.3606737602222409f   // 0.25 * log2(e)

#if defined(__has_builtin)
#if __has_builtin(__builtin_amdgcn_global_load_lds)
#define HAVE_GLL 1
#endif
#endif

using bf16x8 = __attribute__((ext_vector_type(8))) short;
using f32x4  = __attribute__((ext_vector_type(4))) float;

__device__ __forceinline__ unsigned cvtpk(float lo, float hi) {
    unsigned r;
    asm("v_cvt_pk_bf16_f32 %0, %1, %2" : "=v"(r) : "v"(lo), "v"(hi));
    return r;
}
__device__ __forceinline__ unsigned short bf_rne(float x) {
    unsigned u = __float_as_uint(x);
    u += 0x7FFFu + ((u >> 16) & 1u);
    return (unsigned short)(u >> 16);
}
__device__ __forceinline__ float fexp2(float x) {
#if __has_builtin(__builtin_amdgcn_exp2f)
    return __builtin_amdgcn_exp2f(x);
#else
    return __expf(x * 0.69314718055994531f);
#endif
}
#ifdef HAVE_GLL
__device__ __forceinline__ void gload16(const void* g, void* l) {
    __builtin_amdgcn_global_load_lds(
        (const __attribute__((address_space(1))) unsigned int*)g,
        (__attribute__((address_space(3))) unsigned int*)l, 16, 0, 0);
}
#endif

// K [b][c][t] f32 -> kbt [b][t][c] bf16 (RNE), fused k8l = |k|^2/8*log2e
__global__ __launch_bounds__(512)
void stcn_ktr_kernel(const float* __restrict__ mk, unsigned short* __restrict__ kbt,
                     float* __restrict__ k8l) {
    __shared__ unsigned short L[64][72];
    __shared__ float S[64][8];
    const int tid = threadIdx.x, b = blockIdx.y, t0 = blockIdx.x * 64;
    const int tt = tid & 63;
    float a2 = 0.f;
#pragma unroll
    for (int it = 0; it < 8; ++it) {
        int idx = tid + 512 * it;
        int c = idx >> 6;
        int t = t0 + tt;
        float v = (t < THW) ? mk[((size_t)b * CKDIM + c) * THW + t] : 0.f;
        L[tt][c] = bf_rne(v);
        a2 = fmaf(v, v, a2);
    }
    S[tt][tid >> 6] = a2;
    __syncthreads();
    if (tid < 64) {
        float s = 0.f;
#pragma unroll
        for (int q = 0; q < 8; ++q) s += S[tid][q];
        int t = t0 + tid;
        if (t < THW) k8l[b * THW + t] = s * (0.125f * 1.44269504088896341f);
    }
    {
        int tr = tid >> 3, cq = tid & 7;
        int t = t0 + tr;
        if (t < THW) {
            uint4 o = *(const uint4*)&L[tr][8 * cq];
            *(uint4*)(kbt + ((size_t)b * THW + t) * CKDIM + 8 * cq) = o;
        }
    }
}

// V f32 -> bf16 (RNE)
__global__ void stcn_vcvt_kernel(const float* __restrict__ mv, unsigned short* __restrict__ mvb) {
    size_t i = ((size_t)blockIdx.x * 256 + threadIdx.x) * 8;
    if (i >= (size_t)NOBJ * CVAL * THW) return;
    float4 v0 = *(const float4*)(mv + i);
    float4 v1 = *(const float4*)(mv + i + 4);
    uint4 o;
    o.x = cvtpk(v0.x, v0.y); o.y = cvtpk(v0.z, v0.w);
    o.z = cvtpk(v1.x, v1.y); o.w = cvtpk(v1.z, v1.w);
    *(uint4*)(mvb + i) = o;
}

// Mbound[b][j] = (sum_c q^2)/8 * log2e (exact upper bound on log2-logits)
__global__ void stcn_qbound_kernel(const float* __restrict__ qk, float* __restrict__ mbnd) {
    int j = blockIdx.x * 256 + threadIdx.x;
    if (j >= HWDIM) return;
    int b = blockIdx.y;
    const float* p = qk + (size_t)b * CKDIM * HWDIM + j;
    float s = 0.f;
#pragma unroll
    for (int c = 0; c < CKDIM; ++c) { float v = p[(size_t)c * HWDIM]; s = fmaf(v, v, s); }
    mbnd[b * HWDIM + j] = s * (0.125f * 1.44269504088896341f);
}

// ---------------- single-pass P-write: P~ (bf16) -> Pws[slot][j][THW], l~ atomics ----------------
__global__ __launch_bounds__(512)
void stcn_pwrite_kernel(const unsigned short* __restrict__ kbt,
                        const float* __restrict__ qk, const float* __restrict__ k8l,
                        const float* __restrict__ mbnd, float* __restrict__ lws,
                        unsigned short* __restrict__ Pws, int bbase)
{
    __shared__ __align__(16) unsigned char smem[36864];
    unsigned short* KtP  = (unsigned short*)smem;
    float*          k8tP = (float*)(smem + 9216);
    unsigned short* PtP  = (unsigned short*)(smem + 9472);
    unsigned short* QtP  = (unsigned short*)smem;

    const int tid  = threadIdx.x;
    const int w    = tid >> 6;
    const int lane = tid & 63;
    const int g    = lane >> 4;
    const int lr   = lane & 15;

    const int bb = blockIdx.y;
    const int b  = bbase + bb;
    const int jt = blockIdx.x >> 4, kc = blockIdx.x & 15;
    const int jbase = jt * 128;

#pragma unroll
    for (int it = 0; it < 8; ++it) {
        int idx = tid + 512 * it;
        int j = idx & 127, cp = idx >> 7;
        int jg = jbase + j;
        float q0 = 0.f, q1 = 0.f;
        if (jg < HWDIM) {
            const float* qp = qk + ((size_t)b * CKDIM + 2 * cp) * HWDIM + jg;
            q0 = qp[0]; q1 = qp[HWDIM];
        }
        unsigned wh = cvtpk(q0, q1);
        float r0 = q0 - __uint_as_float(wh << 16);
        float r1 = q1 - __uint_as_float(wh & 0xFFFF0000u);
        *(unsigned*)&QtP[(0 * 128 + j) * 72 + 2 * cp] = wh;
        *(unsigned*)&QtP[(1 * 128 + j) * 72 + 2 * cp] = cvtpk(r0, r1);
    }
    __syncthreads();
    bf16x8 bqh[2], bql[2];
#pragma unroll
    for (int s = 0; s < 2; ++s) {
        bqh[s] = *(const bf16x8*)&QtP[(0 * 128 + w * 16 + lr) * 72 + 32 * s + 8 * g];
        bql[s] = *(const bf16x8*)&QtP[(1 * 128 + w * 16 + lr) * 72 + 32 * s + 8 * g];
    }
    __syncthreads();   // Qt dead

    const int s0 = (NSTEP * kc) / PCH, s1 = (NSTEP * (kc + 1)) / PCH;

    const int jgq = jbase + w * 16 + lr;
    const float mv_j = (jgq < HWDIM) ? mbnd[b * HWDIM + jgq] : 0.f;
    float lsum = 0.f;

    {
        int tt = tid >> 4, cq = tid & 15;
        uint2 k16 = *(const uint2*)(kbt + ((size_t)b * THW + s0 * 32 + tt) * CKDIM + 4 * cq);
        *(uint2*)&KtP[tt * 72 + 4 * cq] = k16;
        if (tid < 32) k8tP[tid] = k8l[b * THW + s0 * 32 + tid];
    }
    __syncthreads();

    f32x4 zz = {0.f, 0.f, 0.f, 0.f};
    int cur = 0;
    for (int st = s0; st < s1; ++st) {
        const int t0 = st * 32;
        const bool nxt = (st + 1 < s1);
        uint2 k16;
        float k8next = 0.f;
        const int tt = tid >> 4, cq = tid & 15;
        if (nxt) {
            k16 = *(const uint2*)(kbt + ((size_t)b * THW + (st + 1) * 32 + tt) * CKDIM + 4 * cq);
            if (tid < 32) k8next = k8l[b * THW + (st + 1) * 32 + tid];
        }
        bf16x8 ak0[2], ak1[2];
#pragma unroll
        for (int s = 0; s < 2; ++s) {
            ak0[s] = *(const bf16x8*)&KtP[(cur * 32 + lr) * 72 + 32 * s + 8 * g];
            ak1[s] = *(const bf16x8*)&KtP[(cur * 32 + 16 + lr) * 72 + 32 * s + 8 * g];
        }
        f32x4 k80 = *(const f32x4*)&k8tP[cur * 32 + 4 * g];
        f32x4 k81 = *(const f32x4*)&k8tP[cur * 32 + 16 + 4 * g];
        f32x4 ab0 = zz, ab1 = zz;
#pragma unroll
        for (int s = 0; s < 2; ++s) {
            ab0 = __builtin_amdgcn_mfma_f32_16x16x32_bf16(ak0[s], bqh[s], ab0, 0, 0, 0);
            ab0 = __builtin_amdgcn_mfma_f32_16x16x32_bf16(ak0[s], bql[s], ab0, 0, 0, 0);
            ab1 = __builtin_amdgcn_mfma_f32_16x16x32_bf16(ak1[s], bqh[s], ab1, 0, 0, 0);
            ab1 = __builtin_amdgcn_mfma_f32_16x16x32_bf16(ak1[s], bql[s], ab1, 0, 0, 0);
        }
        if (nxt) {
            *(uint2*)&KtP[((cur ^ 1) * 32 + tt) * 72 + 4 * cq] = k16;
            if (tid < 32) k8tP[(cur ^ 1) * 32 + tid] = k8next;
        }
        float p0[4], p1[4];
#pragma unroll
        for (int r = 0; r < 4; ++r) {
            p0[r] = fexp2(fmaf(ab0[r], S2F, -k80[r]) - mv_j);
            p1[r] = fexp2(fmaf(ab1[r], S2F, -k81[r]) - mv_j);
        }
        lsum += (p0[0] + p0[1] + p0[2] + p0[3]) + (p1[0] + p1[1] + p1[2] + p1[3]);
        __syncthreads();
        {
            int jl = w * 16 + lr;
            *(uint2*)&PtP[jl * 56 + 4 * g]      = make_uint2(cvtpk(p0[0], p0[1]), cvtpk(p0[2], p0[3]));
            *(uint2*)&PtP[jl * 56 + 16 + 4 * g] = make_uint2(cvtpk(p1[0], p1[1]), cvtpk(p1[2], p1[3]));
        }
        __syncthreads();
        {
            int jr = tid >> 2, qq = tid & 3;
            int jg = jbase + jr;
            if (jg < HWDIM)
                *(uint4*)(Pws + ((size_t)bb * HWDIM + jg) * THW + t0 + qq * 8) =
                    *(const uint4*)&PtP[jr * 56 + qq * 8];
        }
        cur ^= 1;
    }

    lsum += __shfl_xor(lsum, 16, 64);
    lsum += __shfl_xor(lsum, 32, 64);
    if (g == 0 && jgq < HWDIM)
        atomicAdd(&lws[b * HWDIM + jgq], lsum);
}

// ---------------- GEMM v7: 128x128 tile, BK=64 (two 32-col sub-tiles / barrier window) ----------------
// 4 waves of 64x64; each buffer = 2 sub-tiles of 16KB (layout identical to the proven gemm3 tile);
// ONE __syncthreads per 2 K-steps -> half the barrier/waitcnt overhead per MFMA.
// FULLP: 1-D grid 1664 = 8n x 4cm x 13jn x 4ks, XCD-bijective.
template <bool FULLP>
__global__ __launch_bounds__(256, 2)
void stcn_gemm7_kernel(const unsigned short* __restrict__ mvb,
                       const unsigned short* __restrict__ Pws,
                       const float* __restrict__ lws,
                       const int* __restrict__ bmap, float* __restrict__ out, int phase)
{
    __shared__ __align__(16) unsigned short Av[2][2 * 128 * 32];   // 2 buf x 2 sub x 8KB... 32KB total
    __shared__ __align__(16) unsigned short Bv[2][2 * 128 * 32];

    int n, cm, jn, ks, ksplit, bslot;
    if constexpr (FULLP) {
        int wg  = blockIdx.x;                      // 1664
        int vid = (wg & 7) * 208 + (wg >> 3);      // bijective: each XCD owns one n
        n = vid / 208;
        int r  = vid % 208;
        cm = r / 52;
        int r2 = r % 52;
        jn = r2 >> 2;
        ks = r2 & 3;
        ksplit = 4;
    } else {
        n = blockIdx.y;
        const int x = blockIdx.x;                  // 2ks x 13jn x 4cm = 104
        ks = x & 1;
        const int rest = x >> 1;
        jn = rest % NJT;
        cm = rest / NJT;
        ksplit = 2;
    }
    const int b = bmap[n];
    if constexpr (FULLP) { bslot = b; }
    else { if ((b >> 1) != phase) return; bslot = b & 1; }

    const int jbase = jn * 128, cbase = cm * 128;

    const int tid = threadIdx.x;          // 256
    const int w = tid >> 6, lane = tid & 63, g = lane >> 4, lr = lane & 15;
    const int wc = w >> 1, wj = w & 1;    // 2x2 wave grid, 64x64 per wave

    const int srow = tid >> 2;
    const int tsw  = (((tid & 3) ^ ((tid >> 3) & 3)) << 3);   // pre-swizzled source t-offset
    const int gs8  = ((g ^ ((lr >> 1) & 3)) << 3);            // read-side swizzle

    const int s0 = (NSTEP * ks) / ksplit, s1 = (NSTEP * (ks + 1)) / ksplit;

    const unsigned short* abase = mvb + ((size_t)n * CVAL + cbase) * THW;
    const unsigned short* bbase = Pws + (size_t)bslot * HWDIM * THW;
    int jr0 = jbase + srow;       if (jr0 >= HWDIM) jr0 = 0;
    int jr1 = jbase + 64 + srow;  if (jr1 >= HWDIM) jr1 = 0;
    const unsigned short* ga0 = abase + (size_t)(srow) * THW + tsw;
    const unsigned short* ga1 = abase + (size_t)(64 + srow) * THW + tsw;
    const unsigned short* gb0 = bbase + (size_t)jr0 * THW + tsw;
    const unsigned short* gb1 = bbase + (size_t)jr1 * THW + tsw;

    f32x4 zz = {0.f, 0.f, 0.f, 0.f};
    f32x4 acc[4][4];
#pragma unroll
    for (int i = 0; i < 4; ++i)
#pragma unroll
        for (int j = 0; j < 4; ++j) acc[i][j] = zz;

#ifdef HAVE_GLL
    // stage one 32-col sub-tile (identical pattern to proven gemm3 tile)
    auto stage_sub = [&](int buf, int sub, int st) {
        const int t0 = st * 32;
        const int so = sub * 4096;
        gload16(ga0 + t0, &Av[buf][so + 0    + w * 512]);
        gload16(ga1 + t0, &Av[buf][so + 2048 + w * 512]);
        gload16(gb0 + t0, &Bv[buf][so + 0    + w * 512]);
        gload16(gb1 + t0, &Bv[buf][so + 2048 + w * 512]);
    };
#else
    auto stage_sub_reg = [&](int st, uint4* r4) {
        const int t0 = st * 32;
        r4[0] = *(const uint4*)(ga0 + t0);
        r4[1] = *(const uint4*)(ga1 + t0);
        r4[2] = *(const uint4*)(gb0 + t0);
        r4[3] = *(const uint4*)(gb1 + t0);
    };
    auto write_sub = [&](int buf, int sub, const uint4* r4) {
        const int so = sub * 4096;
        *(uint4*)&Av[buf][so + tid * 8]        = r4[0];
        *(uint4*)&Av[buf][so + 2048 + tid * 8] = r4[1];
        *(uint4*)&Bv[buf][so + tid * 8]        = r4[2];
        *(uint4*)&Bv[buf][so + 2048 + tid * 8] = r4[3];
    };
#endif

    // compute one 32-col sub-tile: 8 ds_read_b128 + 16 MFMA
    auto compute_sub = [&](int buf, int sub) {
        const int so = sub * 4096;
        bf16x8 av[4], bp[4];
#pragma unroll
        for (int cf = 0; cf < 4; ++cf)
            av[cf] = *(const bf16x8*)&Av[buf][so + (wc * 64 + cf * 16 + lr) * 32 + gs8];
#pragma unroll
        for (int jf = 0; jf < 4; ++jf)
            bp[jf] = *(const bf16x8*)&Bv[buf][so + (wj * 64 + jf * 16 + lr) * 32 + gs8];
#pragma unroll
        for (int cf = 0; cf < 4; ++cf)
#pragma unroll
            for (int jf = 0; jf < 4; ++jf)
                acc[cf][jf] = __builtin_amdgcn_mfma_f32_16x16x32_bf16(av[cf], bp[jf], acc[cf][jf], 0, 0, 0);
    };

    // prologue: stage pair (s0, s0+1) into buf 0
#ifdef HAVE_GLL
    stage_sub(0, 0, s0);
    if (s0 + 1 < s1) stage_sub(0, 1, s0 + 1);
#else
    {
        uint4 r0[4], r1[4];
        stage_sub_reg(s0, r0);
        write_sub(0, 0, r0);
        if (s0 + 1 < s1) { stage_sub_reg(s0 + 1, r1); write_sub(0, 1, r1); }
    }
#endif
    __syncthreads();

    int cur = 0;
    for (int st = s0; st < s1; st += 2) {
        const int rem  = s1 - st;              // >= 1
        const bool nxt = (st + 2 < s1);
#ifdef HAVE_GLL
        if (nxt) {
            stage_sub(cur ^ 1, 0, st + 2);
            if (st + 3 < s1) stage_sub(cur ^ 1, 1, st + 3);
        }
        compute_sub(cur, 0);
        if (rem > 1) compute_sub(cur, 1);
#else
        uint4 r0[4], r1[4];
        bool h3 = false;
        if (nxt) {
            stage_sub_reg(st + 2, r0);
            if (st + 3 < s1) { stage_sub_reg(st + 3, r1); h3 = true; }
        }
        compute_sub(cur, 0);
        if (rem > 1) compute_sub(cur, 1);
        if (nxt) {
            write_sub(cur ^ 1, 0, r0);
            if (h3) write_sub(cur ^ 1, 1, r1);
        }
#endif
        __syncthreads();   // drains gloads/ds; next buffer ready, cur free for restage
        cur ^= 1;
    }

    // epilogue: scale by 1/l~(b, j) then atomic-accumulate
    float il[4];
#pragma unroll
    for (int jf = 0; jf < 4; ++jf) {
        int jg = jbase + wj * 64 + jf * 16 + lr;
        il[jf] = (jg < HWDIM) ? 1.0f / lws[b * HWDIM + jg] : 0.f;
    }
#pragma unroll
    for (int cf = 0; cf < 4; ++cf)
#pragma unroll
        for (int jf = 0; jf < 4; ++jf) {
            int jg = jbase + wj * 64 + jf * 16 + lr;
            if (jg < HWDIM) {
                int c = cbase + wc * 64 + cf * 16 + 4 * g;
                float* op = out + ((size_t)n * CVAL + c) * HWDIM + jg;
#pragma unroll
                for (int r4i = 0; r4i < 4; ++r4i)
                    atomicAdd(op + (size_t)r4i * HWDIM, acc[cf][jf][r4i] * il[jf]);
            }
        }
}

extern "C" void kernel_launch(void* const* d_in, const int* in_sizes, int n_in,
                              void* d_out, int out_size, void* d_ws, size_t ws_size,
                              hipStream_t stream) {
    (void)in_sizes; (void)n_in;
    const float* mk   = (const float*)d_in[0];   // mem_keys   [4,64,12960]
    const float* mv   = (const float*)d_in[1];   // mem_values [8,512,12960]
    const float* qkp  = (const float*)d_in[2];   // qk         [4,64,1620]
    const int*   bmap = (const int*)d_in[3];     // broadcast_map [8]
    float* out = (float*)d_out;

    // ws layout: k8l | mbnd | lws | mvb | kbt | Pws
    float* k8l  = (float*)d_ws;                           // NB*THW
    float* mbnd = k8l + NB * THW;                         // NB*HWDIM
    float* lws  = mbnd + NB * HWDIM;                      // NB*HWDIM
    unsigned short* mvb = (unsigned short*)(lws + NB * HWDIM);
    unsigned short* kbt = mvb + (size_t)NOBJ * CVAL * THW;
    unsigned short* Pws = kbt + (size_t)NB * THW * CKDIM;

    size_t base = ((size_t)NB * THW + 2 * (size_t)NB * HWDIM) * 4;
    size_t mvbB = (size_t)NOBJ * CVAL * THW * 2;
    size_t kbtB = (size_t)NB * THW * CKDIM * 2;
    size_t need_P4 = base + mvbB + kbtB + (size_t)4 * HWDIM * THW * 2;
    bool use_P4 = (ws_size >= need_P4);

    hipMemsetAsync(d_out, 0, (size_t)out_size * sizeof(float), stream);
    hipMemsetAsync(lws, 0, (size_t)NB * HWDIM * sizeof(float), stream);

    stcn_ktr_kernel<<<dim3((THW + 63) / 64, NB), 512, 0, stream>>>(mk, kbt, k8l);
    {
        size_t nthreads = (size_t)NOBJ * CVAL * THW / 8;
        stcn_vcvt_kernel<<<(unsigned)((nthreads + 255) / 256), 256, 0, stream>>>(mv, mvb);
    }
    stcn_qbound_kernel<<<dim3((HWDIM + 255) / 256, NB), 256, 0, stream>>>(qkp, mbnd);

    if (use_P4) {
        stcn_pwrite_kernel<<<dim3(NJT * PCH, NB), 512, 0, stream>>>(
            kbt, qkp, k8l, mbnd, lws, Pws, 0);
        stcn_gemm7_kernel<true><<<dim3(1664), 256, 0, stream>>>(
            mvb, Pws, lws, bmap, out, 0);
    } else {
        for (int p = 0; p < 2; ++p) {
            stcn_pwrite_kernel<<<dim3(NJT * PCH, 2), 512, 0, stream>>>(
                kbt, qkp, k8l, mbnd, lws, Pws, 2 * p);
            stcn_gemm7_kernel<false><<<dim3(104, NOBJ), 256, 0, stream>>>(
                mvb, Pws, lws, bmap, out, p);
        }
    }
}

// Round 15
// 539.925 us; speedup vs baseline: 1.0995x; 1.0995x over previous
//
#include <hip/hip_runtime.h>
#include <hip/hip_bf16.h>

// STCN read_memory: affinity softmax over THW + value readout.
// Single-S-pass: P~ = exp2(L - Mbound(j)), l~(j) = sum_t P~; out = (sum P~ V)/l~.
// Mbound = |q|^2/8*log2e >= L exactly (2aq - a^2 = q^2 - |q-a|^2).
#define CKDIM 64
#define THW   12960     // 8*30*54
#define HWDIM 1620      // 30*54
#define NOBJ  8
#define CVAL  512
#define NB    4
#define NSTEP 405       // THW / 32
#define NJT   13        // ceil(1620/128)
#define PCH   24        // P-write K-chunks (16->24: ~4.9 blocks/CU queue)
#define S2F   0.3606737602222409f   // 0.25 * log2(e)

#if defined(__has_builtin)
#if __has_builtin(__builtin_amdgcn_global_load_lds)
#define HAVE_GLL 1
#endif
#endif

using bf16x8 = __attribute__((ext_vector_type(8))) short;
using f32x4  = __attribute__((ext_vector_type(4))) float;

__device__ __forceinline__ unsigned cvtpk(float lo, float hi) {
    unsigned r;
    asm("v_cvt_pk_bf16_f32 %0, %1, %2" : "=v"(r) : "v"(lo), "v"(hi));
    return r;
}
__device__ __forceinline__ unsigned short bf_rne(float x) {
    unsigned u = __float_as_uint(x);
    u += 0x7FFFu + ((u >> 16) & 1u);
    return (unsigned short)(u >> 16);
}
__device__ __forceinline__ float fexp2(float x) {
#if __has_builtin(__builtin_amdgcn_exp2f)
    return __builtin_amdgcn_exp2f(x);
#else
    return __expf(x * 0.69314718055994531f);
#endif
}
#ifdef HAVE_GLL
__device__ __forceinline__ void gload16(const void* g, void* l) {
    __builtin_amdgcn_global_load_lds(
        (const __attribute__((address_space(1))) unsigned int*)g,
        (__attribute__((address_space(3))) unsigned int*)l, 16, 0, 0);
}
#endif

// K [b][c][t] f32 -> kbt [b][t][c] bf16 (RNE), fused k8l = |k|^2/8*log2e
__global__ __launch_bounds__(512)
void stcn_ktr_kernel(const float* __restrict__ mk, unsigned short* __restrict__ kbt,
                     float* __restrict__ k8l) {
    __shared__ unsigned short L[64][72];
    __shared__ float S[64][8];
    const int tid = threadIdx.x, b = blockIdx.y, t0 = blockIdx.x * 64;
    const int tt = tid & 63;
    float a2 = 0.f;
#pragma unroll
    for (int it = 0; it < 8; ++it) {
        int idx = tid + 512 * it;
        int c = idx >> 6;
        int t = t0 + tt;
        float v = (t < THW) ? mk[((size_t)b * CKDIM + c) * THW + t] : 0.f;
        L[tt][c] = bf_rne(v);
        a2 = fmaf(v, v, a2);
    }
    S[tt][tid >> 6] = a2;
    __syncthreads();
    if (tid < 64) {
        float s = 0.f;
#pragma unroll
        for (int q = 0; q < 8; ++q) s += S[tid][q];
        int t = t0 + tid;
        if (t < THW) k8l[b * THW + t] = s * (0.125f * 1.44269504088896341f);
    }
    {
        int tr = tid >> 3, cq = tid & 7;
        int t = t0 + tr;
        if (t < THW) {
            uint4 o = *(const uint4*)&L[tr][8 * cq];
            *(uint4*)(kbt + ((size_t)b * THW + t) * CKDIM + 8 * cq) = o;
        }
    }
}

// V f32 -> bf16 (RNE)
__global__ void stcn_vcvt_kernel(const float* __restrict__ mv, unsigned short* __restrict__ mvb) {
    size_t i = ((size_t)blockIdx.x * 256 + threadIdx.x) * 8;
    if (i >= (size_t)NOBJ * CVAL * THW) return;
    float4 v0 = *(const float4*)(mv + i);
    float4 v1 = *(const float4*)(mv + i + 4);
    uint4 o;
    o.x = cvtpk(v0.x, v0.y); o.y = cvtpk(v0.z, v0.w);
    o.z = cvtpk(v1.x, v1.y); o.w = cvtpk(v1.z, v1.w);
    *(uint4*)(mvb + i) = o;
}

// Mbound[b][j] = (sum_c q^2)/8 * log2e (exact upper bound on log2-logits)
__global__ void stcn_qbound_kernel(const float* __restrict__ qk, float* __restrict__ mbnd) {
    int j = blockIdx.x * 256 + threadIdx.x;
    if (j >= HWDIM) return;
    int b = blockIdx.y;
    const float* p = qk + (size_t)b * CKDIM * HWDIM + j;
    float s = 0.f;
#pragma unroll
    for (int c = 0; c < CKDIM; ++c) { float v = p[(size_t)c * HWDIM]; s = fmaf(v, v, s); }
    mbnd[b * HWDIM + j] = s * (0.125f * 1.44269504088896341f);
}

// ---------------- single-pass P-write: P~ (bf16) -> Pws[slot][j][THW], l~ atomics ----------------
__global__ __launch_bounds__(512)
void stcn_pwrite_kernel(const unsigned short* __restrict__ kbt,
                        const float* __restrict__ qk, const float* __restrict__ k8l,
                        const float* __restrict__ mbnd, float* __restrict__ lws,
                        unsigned short* __restrict__ Pws, int bbase)
{
    __shared__ __align__(16) unsigned char smem[36864];
    unsigned short* KtP  = (unsigned short*)smem;
    float*          k8tP = (float*)(smem + 9216);
    unsigned short* PtP  = (unsigned short*)(smem + 9472);
    unsigned short* QtP  = (unsigned short*)smem;

    const int tid  = threadIdx.x;
    const int w    = tid >> 6;
    const int lane = tid & 63;
    const int g    = lane >> 4;
    const int lr   = lane & 15;

    const int bb = blockIdx.y;
    const int b  = bbase + bb;
    const int jt = blockIdx.x / PCH, kc = blockIdx.x % PCH;
    const int jbase = jt * 128;

#pragma unroll
    for (int it = 0; it < 8; ++it) {
        int idx = tid + 512 * it;
        int j = idx & 127, cp = idx >> 7;
        int jg = jbase + j;
        float q0 = 0.f, q1 = 0.f;
        if (jg < HWDIM) {
            const float* qp = qk + ((size_t)b * CKDIM + 2 * cp) * HWDIM + jg;
            q0 = qp[0]; q1 = qp[HWDIM];
        }
        unsigned wh = cvtpk(q0, q1);
        float r0 = q0 - __uint_as_float(wh << 16);
        float r1 = q1 - __uint_as_float(wh & 0xFFFF0000u);
        *(unsigned*)&QtP[(0 * 128 + j) * 72 + 2 * cp] = wh;
        *(unsigned*)&QtP[(1 * 128 + j) * 72 + 2 * cp] = cvtpk(r0, r1);
    }
    __syncthreads();
    bf16x8 bqh[2], bql[2];
#pragma unroll
    for (int s = 0; s < 2; ++s) {
        bqh[s] = *(const bf16x8*)&QtP[(0 * 128 + w * 16 + lr) * 72 + 32 * s + 8 * g];
        bql[s] = *(const bf16x8*)&QtP[(1 * 128 + w * 16 + lr) * 72 + 32 * s + 8 * g];
    }
    __syncthreads();   // Qt dead

    const int s0 = (NSTEP * kc) / PCH, s1 = (NSTEP * (kc + 1)) / PCH;

    const int jgq = jbase + w * 16 + lr;
    const float mv_j = (jgq < HWDIM) ? mbnd[b * HWDIM + jgq] : 0.f;
    float lsum = 0.f;

    {
        int tt = tid >> 4, cq = tid & 15;
        uint2 k16 = *(const uint2*)(kbt + ((size_t)b * THW + s0 * 32 + tt) * CKDIM + 4 * cq);
        *(uint2*)&KtP[tt * 72 + 4 * cq] = k16;
        if (tid < 32) k8tP[tid] = k8l[b * THW + s0 * 32 + tid];
    }
    __syncthreads();

    f32x4 zz = {0.f, 0.f, 0.f, 0.f};
    int cur = 0;
    for (int st = s0; st < s1; ++st) {
        const int t0 = st * 32;
        const bool nxt = (st + 1 < s1);
        uint2 k16;
        float k8next = 0.f;
        const int tt = tid >> 4, cq = tid & 15;
        if (nxt) {
            k16 = *(const uint2*)(kbt + ((size_t)b * THW + (st + 1) * 32 + tt) * CKDIM + 4 * cq);
            if (tid < 32) k8next = k8l[b * THW + (st + 1) * 32 + tid];
        }
        bf16x8 ak0[2], ak1[2];
#pragma unroll
        for (int s = 0; s < 2; ++s) {
            ak0[s] = *(const bf16x8*)&KtP[(cur * 32 + lr) * 72 + 32 * s + 8 * g];
            ak1[s] = *(const bf16x8*)&KtP[(cur * 32 + 16 + lr) * 72 + 32 * s + 8 * g];
        }
        f32x4 k80 = *(const f32x4*)&k8tP[cur * 32 + 4 * g];
        f32x4 k81 = *(const f32x4*)&k8tP[cur * 32 + 16 + 4 * g];
        f32x4 ab0 = zz, ab1 = zz;
#pragma unroll
        for (int s = 0; s < 2; ++s) {
            ab0 = __builtin_amdgcn_mfma_f32_16x16x32_bf16(ak0[s], bqh[s], ab0, 0, 0, 0);
            ab0 = __builtin_amdgcn_mfma_f32_16x16x32_bf16(ak0[s], bql[s], ab0, 0, 0, 0);
            ab1 = __builtin_amdgcn_mfma_f32_16x16x32_bf16(ak1[s], bqh[s], ab1, 0, 0, 0);
            ab1 = __builtin_amdgcn_mfma_f32_16x16x32_bf16(ak1[s], bql[s], ab1, 0, 0, 0);
        }
        if (nxt) {
            *(uint2*)&KtP[((cur ^ 1) * 32 + tt) * 72 + 4 * cq] = k16;
            if (tid < 32) k8tP[(cur ^ 1) * 32 + tid] = k8next;
        }
        float p0[4], p1[4];
#pragma unroll
        for (int r = 0; r < 4; ++r) {
            p0[r] = fexp2(fmaf(ab0[r], S2F, -k80[r]) - mv_j);
            p1[r] = fexp2(fmaf(ab1[r], S2F, -k81[r]) - mv_j);
        }
        lsum += (p0[0] + p0[1] + p0[2] + p0[3]) + (p1[0] + p1[1] + p1[2] + p1[3]);
        __syncthreads();
        {
            int jl = w * 16 + lr;
            *(uint2*)&PtP[jl * 56 + 4 * g]      = make_uint2(cvtpk(p0[0], p0[1]), cvtpk(p0[2], p0[3]));
            *(uint2*)&PtP[jl * 56 + 16 + 4 * g] = make_uint2(cvtpk(p1[0], p1[1]), cvtpk(p1[2], p1[3]));
        }
        __syncthreads();
        {
            int jr = tid >> 2, qq = tid & 3;
            int jg = jbase + jr;
            if (jg < HWDIM)
                *(uint4*)(Pws + ((size_t)bb * HWDIM + jg) * THW + t0 + qq * 8) =
                    *(const uint4*)&PtP[jr * 56 + qq * 8];
        }
        cur ^= 1;
    }

    lsum += __shfl_xor(lsum, 16, 64);
    lsum += __shfl_xor(lsum, 32, 64);
    if (g == 0 && jgq < HWDIM)
        atomicAdd(&lws[b * HWDIM + jgq], lsum);
}

// ---------------- GEMM (proven): out[n][c][j] += (sum_t V P~) / l~(b,j) ----------------
// 128c x 128j tile, 4 waves of 64x64, BK=32, global_load_lds dbuf, slot-XOR swizzle.
// FULLP: 1-D grid 1664 = 8n x 4cm x 13jn x 4ks, XCD-bijective (one n per XCD).
template <bool FULLP>
__global__ __launch_bounds__(256, 4)
void stcn_gemm3_kernel(const unsigned short* __restrict__ mvb,
                       const unsigned short* __restrict__ Pws,
                       const float* __restrict__ lws,
                       const int* __restrict__ bmap, float* __restrict__ out, int phase)
{
    __shared__ __align__(16) unsigned short Av[2][128 * 32];
    __shared__ __align__(16) unsigned short Bv[2][128 * 32];

    int n, cm, jn, ks, ksplit, bslot;
    if constexpr (FULLP) {
        int wg  = blockIdx.x;                      // 1664
        int vid = (wg & 7) * 208 + (wg >> 3);      // bijective: each XCD owns one n
        n = vid / 208;
        int r  = vid % 208;
        cm = r / 52;
        int r2 = r % 52;
        jn = r2 >> 2;
        ks = r2 & 3;
        ksplit = 4;
    } else {
        n = blockIdx.y;
        const int x = blockIdx.x;                  // 2ks x 13jn x 4cm = 104
        ks = x & 1;
        const int rest = x >> 1;
        jn = rest % NJT;
        cm = rest / NJT;
        ksplit = 2;
    }
    const int b = bmap[n];
    if constexpr (FULLP) { bslot = b; }
    else { if ((b >> 1) != phase) return; bslot = b & 1; }

    const int jbase = jn * 128, cbase = cm * 128;

    const int tid = threadIdx.x;          // 256
    const int w = tid >> 6, lane = tid & 63, g = lane >> 4, lr = lane & 15;
    const int wc = w >> 1, wj = w & 1;    // 2x2 wave grid, 64x64 per wave

    const int srow = tid >> 2;
    const int tsw  = (((tid & 3) ^ ((tid >> 3) & 3)) << 3);   // pre-swizzled source t-offset
    const int gs8  = ((g ^ ((lr >> 1) & 3)) << 3);            // read-side swizzle

    const int s0 = (NSTEP * ks) / ksplit, s1 = (NSTEP * (ks + 1)) / ksplit;

    const unsigned short* abase = mvb + ((size_t)n * CVAL + cbase) * THW;
    const unsigned short* bbase = Pws + (size_t)bslot * HWDIM * THW;
    int jr0 = jbase + srow;       if (jr0 >= HWDIM) jr0 = 0;
    int jr1 = jbase + 64 + srow;  if (jr1 >= HWDIM) jr1 = 0;
    const unsigned short* ga0 = abase + (size_t)(srow) * THW + tsw;
    const unsigned short* ga1 = abase + (size_t)(64 + srow) * THW + tsw;
    const unsigned short* gb0 = bbase + (size_t)jr0 * THW + tsw;
    const unsigned short* gb1 = bbase + (size_t)jr1 * THW + tsw;

    f32x4 zz = {0.f, 0.f, 0.f, 0.f};
    f32x4 acc[4][4];
#pragma unroll
    for (int i = 0; i < 4; ++i)
#pragma unroll
        for (int j = 0; j < 4; ++j) acc[i][j] = zz;

#ifdef HAVE_GLL
    auto stage = [&](int buf, int st) {
        const int t0 = st * 32;
        gload16(ga0 + t0, &Av[buf][0    + w * 512]);
        gload16(ga1 + t0, &Av[buf][2048 + w * 512]);
        gload16(gb0 + t0, &Bv[buf][0    + w * 512]);
        gload16(gb1 + t0, &Bv[buf][2048 + w * 512]);
    };
    stage(0, s0);
#else
    {
        const int t0 = s0 * 32;
        *(uint4*)&Av[0][tid * 8]        = *(const uint4*)(ga0 + t0);
        *(uint4*)&Av[0][2048 + tid * 8] = *(const uint4*)(ga1 + t0);
        *(uint4*)&Bv[0][tid * 8]        = *(const uint4*)(gb0 + t0);
        *(uint4*)&Bv[0][2048 + tid * 8] = *(const uint4*)(gb1 + t0);
    }
#endif
    __syncthreads();

    int cur = 0;
    for (int st = s0; st < s1; ++st) {
        const bool nxt = (st + 1 < s1);
#ifdef HAVE_GLL
        if (nxt) stage(cur ^ 1, st + 1);
#else
        uint4 ra0, ra1, rb0, rb1;
        if (nxt) {
            const int t0 = (st + 1) * 32;
            ra0 = *(const uint4*)(ga0 + t0);
            ra1 = *(const uint4*)(ga1 + t0);
            rb0 = *(const uint4*)(gb0 + t0);
            rb1 = *(const uint4*)(gb1 + t0);
        }
#endif
        bf16x8 av[4], bp[4];
#pragma unroll
        for (int cf = 0; cf < 4; ++cf)
            av[cf] = *(const bf16x8*)&Av[cur][(wc * 64 + cf * 16 + lr) * 32 + gs8];
#pragma unroll
        for (int jf = 0; jf < 4; ++jf)
            bp[jf] = *(const bf16x8*)&Bv[cur][(wj * 64 + jf * 16 + lr) * 32 + gs8];
#pragma unroll
        for (int cf = 0; cf < 4; ++cf)
#pragma unroll
            for (int jf = 0; jf < 4; ++jf)
                acc[cf][jf] = __builtin_amdgcn_mfma_f32_16x16x32_bf16(av[cf], bp[jf], acc[cf][jf], 0, 0, 0);
#ifndef HAVE_GLL
        if (nxt) {
            *(uint4*)&Av[cur ^ 1][tid * 8]        = ra0;
            *(uint4*)&Av[cur ^ 1][2048 + tid * 8] = ra1;
            *(uint4*)&Bv[cur ^ 1][tid * 8]        = rb0;
            *(uint4*)&Bv[cur ^ 1][2048 + tid * 8] = rb1;
        }
#endif
        __syncthreads();
        cur ^= 1;
    }

    // epilogue: scale by 1/l~(b, j) then atomic-accumulate
    float il[4];
#pragma unroll
    for (int jf = 0; jf < 4; ++jf) {
        int jg = jbase + wj * 64 + jf * 16 + lr;
        il[jf] = (jg < HWDIM) ? 1.0f / lws[b * HWDIM + jg] : 0.f;
    }
#pragma unroll
    for (int cf = 0; cf < 4; ++cf)
#pragma unroll
        for (int jf = 0; jf < 4; ++jf) {
            int jg = jbase + wj * 64 + jf * 16 + lr;
            if (jg < HWDIM) {
                int c = cbase + wc * 64 + cf * 16 + 4 * g;
                float* op = out + ((size_t)n * CVAL + c) * HWDIM + jg;
#pragma unroll
                for (int r4i = 0; r4i < 4; ++r4i)
                    atomicAdd(op + (size_t)r4i * HWDIM, acc[cf][jf][r4i] * il[jf]);
            }
        }
}

extern "C" void kernel_launch(void* const* d_in, const int* in_sizes, int n_in,
                              void* d_out, int out_size, void* d_ws, size_t ws_size,
                              hipStream_t stream) {
    (void)in_sizes; (void)n_in;
    const float* mk   = (const float*)d_in[0];   // mem_keys   [4,64,12960]
    const float* mv   = (const float*)d_in[1];   // mem_values [8,512,12960]
    const float* qkp  = (const float*)d_in[2];   // qk         [4,64,1620]
    const int*   bmap = (const int*)d_in[3];     // broadcast_map [8]
    float* out = (float*)d_out;

    // ws layout: k8l | mbnd | lws | mvb | kbt | Pws
    float* k8l  = (float*)d_ws;                           // NB*THW
    float* mbnd = k8l + NB * THW;                         // NB*HWDIM
    float* lws  = mbnd + NB * HWDIM;                      // NB*HWDIM
    unsigned short* mvb = (unsigned short*)(lws + NB * HWDIM);
    unsigned short* kbt = mvb + (size_t)NOBJ * CVAL * THW;
    unsigned short* Pws = kbt + (size_t)NB * THW * CKDIM;

    size_t base = ((size_t)NB * THW + 2 * (size_t)NB * HWDIM) * 4;
    size_t mvbB = (size_t)NOBJ * CVAL * THW * 2;
    size_t kbtB = (size_t)NB * THW * CKDIM * 2;
    size_t need_P4 = base + mvbB + kbtB + (size_t)4 * HWDIM * THW * 2;
    bool use_P4 = (ws_size >= need_P4);

    hipMemsetAsync(d_out, 0, (size_t)out_size * sizeof(float), stream);
    hipMemsetAsync(lws, 0, (size_t)NB * HWDIM * sizeof(float), stream);

    stcn_ktr_kernel<<<dim3((THW + 63) / 64, NB), 512, 0, stream>>>(mk, kbt, k8l);
    {
        size_t nthreads = (size_t)NOBJ * CVAL * THW / 8;
        stcn_vcvt_kernel<<<(unsigned)((nthreads + 255) / 256), 256, 0, stream>>>(mv, mvb);
    }
    stcn_qbound_kernel<<<dim3((HWDIM + 255) / 256, NB), 256, 0, stream>>>(qkp, mbnd);

    if (use_P4) {
        // one P pass for all 4 batches + one big GEMM
        stcn_pwrite_kernel<<<dim3(NJT * PCH, NB), 512, 0, stream>>>(
            kbt, qkp, k8l, mbnd, lws, Pws, 0);
        stcn_gemm3_kernel<true><<<dim3(1664), 256, 0, stream>>>(
            mvb, Pws, lws, bmap, out, 0);
    } else {
        // phased: P for b in {0,1} then {2,3}; inactive objects early-exit in GEMM
        for (int p = 0; p < 2; ++p) {
            stcn_pwrite_kernel<<<dim3(NJT * PCH, 2), 512, 0, stream>>>(
                kbt, qkp, k8l, mbnd, lws, Pws, 2 * p);
            stcn_gemm3_kernel<false><<<dim3(104, NOBJ), 256, 0, stream>>>(
                mvb, Pws, lws, bmap, out, p);
        }
    }
}

// Round 16
// 515.115 us; speedup vs baseline: 1.1525x; 1.0482x over previous
//
#include <hip/hip_runtime.h>
#include <hip/hip_bf16.h>

// STCN read_memory: affinity softmax over THW + value readout.
// Single-S-pass: P~ = exp2(L - Mbound(j)), l~(j) = sum_t P~; out = (sum P~ V)/l~.
// Mbound = |q|^2/8*log2e >= L exactly (2aq - a^2 = q^2 - |q-a|^2).
#define CKDIM 64
#define THW   12960     // 8*30*54
#define HWDIM 1620      // 30*54
#define NOBJ  8
#define CVAL  512
#define NB    4
#define NSTEP 405       // THW / 32
#define NJT   13        // ceil(1620/128)
#define PCH   16        // P-write K-chunks (R12-proven)
#define S2F   0.3606737602222409f   // 0.25 * log2(e)

#if defined(__has_builtin)
#if __has_builtin(__builtin_amdgcn_global_load_lds)
#define HAVE_GLL 1
#endif
#endif

using bf16x8 = __attribute__((ext_vector_type(8))) short;
using f32x4  = __attribute__((ext_vector_type(4))) float;

__device__ __forceinline__ unsigned cvtpk(float lo, float hi) {
    unsigned r;
    asm("v_cvt_pk_bf16_f32 %0, %1, %2" : "=v"(r) : "v"(lo), "v"(hi));
    return r;
}
__device__ __forceinline__ unsigned short bf_rne(float x) {
    unsigned u = __float_as_uint(x);
    u += 0x7FFFu + ((u >> 16) & 1u);
    return (unsigned short)(u >> 16);
}
__device__ __forceinline__ float fexp2(float x) {
#if __has_builtin(__builtin_amdgcn_exp2f)
    return __builtin_amdgcn_exp2f(x);
#else
    return __expf(x * 0.69314718055994531f);
#endif
}
#ifdef HAVE_GLL
__device__ __forceinline__ void gload16(const void* g, void* l) {
    __builtin_amdgcn_global_load_lds(
        (const __attribute__((address_space(1))) unsigned int*)g,
        (__attribute__((address_space(3))) unsigned int*)l, 16, 0, 0);
}
#endif

// K [b][c][t] f32 -> kbt [b][t][c] bf16 (RNE), fused k8l = |k|^2/8*log2e
__global__ __launch_bounds__(512)
void stcn_ktr_kernel(const float* __restrict__ mk, unsigned short* __restrict__ kbt,
                     float* __restrict__ k8l) {
    __shared__ unsigned short L[64][72];
    __shared__ float S[64][8];
    const int tid = threadIdx.x, b = blockIdx.y, t0 = blockIdx.x * 64;
    const int tt = tid & 63;
    float a2 = 0.f;
#pragma unroll
    for (int it = 0; it < 8; ++it) {
        int idx = tid + 512 * it;
        int c = idx >> 6;
        int t = t0 + tt;
        float v = (t < THW) ? mk[((size_t)b * CKDIM + c) * THW + t] : 0.f;
        L[tt][c] = bf_rne(v);
        a2 = fmaf(v, v, a2);
    }
    S[tt][tid >> 6] = a2;
    __syncthreads();
    if (tid < 64) {
        float s = 0.f;
#pragma unroll
        for (int q = 0; q < 8; ++q) s += S[tid][q];
        int t = t0 + tid;
        if (t < THW) k8l[b * THW + t] = s * (0.125f * 1.44269504088896341f);
    }
    {
        int tr = tid >> 3, cq = tid & 7;
        int t = t0 + tr;
        if (t < THW) {
            uint4 o = *(const uint4*)&L[tr][8 * cq];
            *(uint4*)(kbt + ((size_t)b * THW + t) * CKDIM + 8 * cq) = o;
        }
    }
}

// V f32 -> bf16 (RNE)
__global__ void stcn_vcvt_kernel(const float* __restrict__ mv, unsigned short* __restrict__ mvb) {
    size_t i = ((size_t)blockIdx.x * 256 + threadIdx.x) * 8;
    if (i >= (size_t)NOBJ * CVAL * THW) return;
    float4 v0 = *(const float4*)(mv + i);
    float4 v1 = *(const float4*)(mv + i + 4);
    uint4 o;
    o.x = cvtpk(v0.x, v0.y); o.y = cvtpk(v0.z, v0.w);
    o.z = cvtpk(v1.x, v1.y); o.w = cvtpk(v1.z, v1.w);
    *(uint4*)(mvb + i) = o;
}

// Mbound[b][j] = (sum_c q^2)/8 * log2e (exact upper bound on log2-logits)
__global__ void stcn_qbound_kernel(const float* __restrict__ qk, float* __restrict__ mbnd) {
    int j = blockIdx.x * 256 + threadIdx.x;
    if (j >= HWDIM) return;
    int b = blockIdx.y;
    const float* p = qk + (size_t)b * CKDIM * HWDIM + j;
    float s = 0.f;
#pragma unroll
    for (int c = 0; c < CKDIM; ++c) { float v = p[(size_t)c * HWDIM]; s = fmaf(v, v, s); }
    mbnd[b * HWDIM + j] = s * (0.125f * 1.44269504088896341f);
}

// ---------------- single-pass P-write: P~ (bf16) -> Pws[slot][j][THW], l~ atomics ----------------
__global__ __launch_bounds__(512)
void stcn_pwrite_kernel(const unsigned short* __restrict__ kbt,
                        const float* __restrict__ qk, const float* __restrict__ k8l,
                        const float* __restrict__ mbnd, float* __restrict__ lws,
                        unsigned short* __restrict__ Pws, int bbase)
{
    __shared__ __align__(16) unsigned char smem[36864];
    unsigned short* KtP  = (unsigned short*)smem;
    float*          k8tP = (float*)(smem + 9216);
    unsigned short* PtP  = (unsigned short*)(smem + 9472);
    unsigned short* QtP  = (unsigned short*)smem;

    const int tid  = threadIdx.x;
    const int w    = tid >> 6;
    const int lane = tid & 63;
    const int g    = lane >> 4;
    const int lr   = lane & 15;

    const int bb = blockIdx.y;
    const int b  = bbase + bb;
    const int jt = blockIdx.x / PCH, kc = blockIdx.x % PCH;
    const int jbase = jt * 128;

#pragma unroll
    for (int it = 0; it < 8; ++it) {
        int idx = tid + 512 * it;
        int j = idx & 127, cp = idx >> 7;
        int jg = jbase + j;
        float q0 = 0.f, q1 = 0.f;
        if (jg < HWDIM) {
            const float* qp = qk + ((size_t)b * CKDIM + 2 * cp) * HWDIM + jg;
            q0 = qp[0]; q1 = qp[HWDIM];
        }
        unsigned wh = cvtpk(q0, q1);
        float r0 = q0 - __uint_as_float(wh << 16);
        float r1 = q1 - __uint_as_float(wh & 0xFFFF0000u);
        *(unsigned*)&QtP[(0 * 128 + j) * 72 + 2 * cp] = wh;
        *(unsigned*)&QtP[(1 * 128 + j) * 72 + 2 * cp] = cvtpk(r0, r1);
    }
    __syncthreads();
    bf16x8 bqh[2], bql[2];
#pragma unroll
    for (int s = 0; s < 2; ++s) {
        bqh[s] = *(const bf16x8*)&QtP[(0 * 128 + w * 16 + lr) * 72 + 32 * s + 8 * g];
        bql[s] = *(const bf16x8*)&QtP[(1 * 128 + w * 16 + lr) * 72 + 32 * s + 8 * g];
    }
    __syncthreads();   // Qt dead

    const int s0 = (NSTEP * kc) / PCH, s1 = (NSTEP * (kc + 1)) / PCH;

    const int jgq = jbase + w * 16 + lr;
    const float mv_j = (jgq < HWDIM) ? mbnd[b * HWDIM + jgq] : 0.f;
    float lsum = 0.f;

    {
        int tt = tid >> 4, cq = tid & 15;
        uint2 k16 = *(const uint2*)(kbt + ((size_t)b * THW + s0 * 32 + tt) * CKDIM + 4 * cq);
        *(uint2*)&KtP[tt * 72 + 4 * cq] = k16;
        if (tid < 32) k8tP[tid] = k8l[b * THW + s0 * 32 + tid];
    }
    __syncthreads();

    f32x4 zz = {0.f, 0.f, 0.f, 0.f};
    int cur = 0;
    for (int st = s0; st < s1; ++st) {
        const int t0 = st * 32;
        const bool nxt = (st + 1 < s1);
        uint2 k16;
        float k8next = 0.f;
        const int tt = tid >> 4, cq = tid & 15;
        if (nxt) {
            k16 = *(const uint2*)(kbt + ((size_t)b * THW + (st + 1) * 32 + tt) * CKDIM + 4 * cq);
            if (tid < 32) k8next = k8l[b * THW + (st + 1) * 32 + tid];
        }
        bf16x8 ak0[2], ak1[2];
#pragma unroll
        for (int s = 0; s < 2; ++s) {
            ak0[s] = *(const bf16x8*)&KtP[(cur * 32 + lr) * 72 + 32 * s + 8 * g];
            ak1[s] = *(const bf16x8*)&KtP[(cur * 32 + 16 + lr) * 72 + 32 * s + 8 * g];
        }
        f32x4 k80 = *(const f32x4*)&k8tP[cur * 32 + 4 * g];
        f32x4 k81 = *(const f32x4*)&k8tP[cur * 32 + 16 + 4 * g];
        f32x4 ab0 = zz, ab1 = zz;
#pragma unroll
        for (int s = 0; s < 2; ++s) {
            ab0 = __builtin_amdgcn_mfma_f32_16x16x32_bf16(ak0[s], bqh[s], ab0, 0, 0, 0);
            ab0 = __builtin_amdgcn_mfma_f32_16x16x32_bf16(ak0[s], bql[s], ab0, 0, 0, 0);
            ab1 = __builtin_amdgcn_mfma_f32_16x16x32_bf16(ak1[s], bqh[s], ab1, 0, 0, 0);
            ab1 = __builtin_amdgcn_mfma_f32_16x16x32_bf16(ak1[s], bql[s], ab1, 0, 0, 0);
        }
        if (nxt) {
            *(uint2*)&KtP[((cur ^ 1) * 32 + tt) * 72 + 4 * cq] = k16;
            if (tid < 32) k8tP[(cur ^ 1) * 32 + tid] = k8next;
        }
        float p0[4], p1[4];
#pragma unroll
        for (int r = 0; r < 4; ++r) {
            p0[r] = fexp2(fmaf(ab0[r], S2F, -k80[r]) - mv_j);
            p1[r] = fexp2(fmaf(ab1[r], S2F, -k81[r]) - mv_j);
        }
        lsum += (p0[0] + p0[1] + p0[2] + p0[3]) + (p1[0] + p1[1] + p1[2] + p1[3]);
        __syncthreads();
        {
            int jl = w * 16 + lr;
            *(uint2*)&PtP[jl * 56 + 4 * g]      = make_uint2(cvtpk(p0[0], p0[1]), cvtpk(p0[2], p0[3]));
            *(uint2*)&PtP[jl * 56 + 16 + 4 * g] = make_uint2(cvtpk(p1[0], p1[1]), cvtpk(p1[2], p1[3]));
        }
        __syncthreads();
        {
            int jr = tid >> 2, qq = tid & 3;
            int jg = jbase + jr;
            if (jg < HWDIM)
                *(uint4*)(Pws + ((size_t)bb * HWDIM + jg) * THW + t0 + qq * 8) =
                    *(const uint4*)&PtP[jr * 56 + qq * 8];
        }
        cur ^= 1;
    }

    lsum += __shfl_xor(lsum, 16, 64);
    lsum += __shfl_xor(lsum, 32, 64);
    if (g == 0 && jgq < HWDIM)
        atomicAdd(&lws[b * HWDIM + jgq], lsum);
}

// ---------------- GEMM (proven): out[n][c][j] += (sum_t V P~) / l~(b,j) ----------------
// 128c x 128j tile, 4 waves of 64x64, BK=32, global_load_lds dbuf, slot-XOR swizzle.
// FULLP: 1-D grid 1664 = 8n x 4cm x 4ks x 13jn; XCD-bijective (one n per XCD),
// jn INNERMOST so 13 consecutive blocks per XCD share an L2-resident V quarter-slab.
template <bool FULLP>
__global__ __launch_bounds__(256, 4)
void stcn_gemm3_kernel(const unsigned short* __restrict__ mvb,
                       const unsigned short* __restrict__ Pws,
                       const float* __restrict__ lws,
                       const int* __restrict__ bmap, float* __restrict__ out, int phase)
{
    __shared__ __align__(16) unsigned short Av[2][128 * 32];
    __shared__ __align__(16) unsigned short Bv[2][128 * 32];

    int n, cm, jn, ks, ksplit, bslot;
    if constexpr (FULLP) {
        int wg  = blockIdx.x;                      // 1664
        int vid = (wg & 7) * 208 + (wg >> 3);      // bijective: each XCD owns one n
        n = vid / 208;
        int r  = vid % 208;
        cm = r / 52;
        int r2 = r % 52;
        ks = r2 / 13;                              // jn innermost: 13 consecutive blocks
        jn = r2 % 13;                              //   share V slab (n, cm, ks) in L2
        ksplit = 4;
    } else {
        n = blockIdx.y;
        const int x = blockIdx.x;                  // 2ks x 13jn x 4cm = 104
        ks = x & 1;
        const int rest = x >> 1;
        jn = rest % NJT;
        cm = rest / NJT;
        ksplit = 2;
    }
    const int b = bmap[n];
    if constexpr (FULLP) { bslot = b; }
    else { if ((b >> 1) != phase) return; bslot = b & 1; }

    const int jbase = jn * 128, cbase = cm * 128;

    const int tid = threadIdx.x;          // 256
    const int w = tid >> 6, lane = tid & 63, g = lane >> 4, lr = lane & 15;
    const int wc = w >> 1, wj = w & 1;    // 2x2 wave grid, 64x64 per wave

    const int srow = tid >> 2;
    const int tsw  = (((tid & 3) ^ ((tid >> 3) & 3)) << 3);   // pre-swizzled source t-offset
    const int gs8  = ((g ^ ((lr >> 1) & 3)) << 3);            // read-side swizzle

    const int s0 = (NSTEP * ks) / ksplit, s1 = (NSTEP * (ks + 1)) / ksplit;

    const unsigned short* abase = mvb + ((size_t)n * CVAL + cbase) * THW;
    const unsigned short* bbase = Pws + (size_t)bslot * HWDIM * THW;
    int jr0 = jbase + srow;       if (jr0 >= HWDIM) jr0 = 0;
    int jr1 = jbase + 64 + srow;  if (jr1 >= HWDIM) jr1 = 0;
    const unsigned short* ga0 = abase + (size_t)(srow) * THW + tsw;
    const unsigned short* ga1 = abase + (size_t)(64 + srow) * THW + tsw;
    const unsigned short* gb0 = bbase + (size_t)jr0 * THW + tsw;
    const unsigned short* gb1 = bbase + (size_t)jr1 * THW + tsw;

    f32x4 zz = {0.f, 0.f, 0.f, 0.f};
    f32x4 acc[4][4];
#pragma unroll
    for (int i = 0; i < 4; ++i)
#pragma unroll
        for (int j = 0; j < 4; ++j) acc[i][j] = zz;

#ifdef HAVE_GLL
    auto stage = [&](int buf, int st) {
        const int t0 = st * 32;
        gload16(ga0 + t0, &Av[buf][0    + w * 512]);
        gload16(ga1 + t0, &Av[buf][2048 + w * 512]);
        gload16(gb0 + t0, &Bv[buf][0    + w * 512]);
        gload16(gb1 + t0, &Bv[buf][2048 + w * 512]);
    };
    stage(0, s0);
#else
    {
        const int t0 = s0 * 32;
        *(uint4*)&Av[0][tid * 8]        = *(const uint4*)(ga0 + t0);
        *(uint4*)&Av[0][2048 + tid * 8] = *(const uint4*)(ga1 + t0);
        *(uint4*)&Bv[0][tid * 8]        = *(const uint4*)(gb0 + t0);
        *(uint4*)&Bv[0][2048 + tid * 8] = *(const uint4*)(gb1 + t0);
    }
#endif
    __syncthreads();

    int cur = 0;
    for (int st = s0; st < s1; ++st) {
        const bool nxt = (st + 1 < s1);
#ifdef HAVE_GLL
        if (nxt) stage(cur ^ 1, st + 1);
#else
        uint4 ra0, ra1, rb0, rb1;
        if (nxt) {
            const int t0 = (st + 1) * 32;
            ra0 = *(const uint4*)(ga0 + t0);
            ra1 = *(const uint4*)(ga1 + t0);
            rb0 = *(const uint4*)(gb0 + t0);
            rb1 = *(const uint4*)(gb1 + t0);
        }
#endif
        bf16x8 av[4], bp[4];
#pragma unroll
        for (int cf = 0; cf < 4; ++cf)
            av[cf] = *(const bf16x8*)&Av[cur][(wc * 64 + cf * 16 + lr) * 32 + gs8];
#pragma unroll
        for (int jf = 0; jf < 4; ++jf)
            bp[jf] = *(const bf16x8*)&Bv[cur][(wj * 64 + jf * 16 + lr) * 32 + gs8];
#pragma unroll
        for (int cf = 0; cf < 4; ++cf)
#pragma unroll
            for (int jf = 0; jf < 4; ++jf)
                acc[cf][jf] = __builtin_amdgcn_mfma_f32_16x16x32_bf16(av[cf], bp[jf], acc[cf][jf], 0, 0, 0);
#ifndef HAVE_GLL
        if (nxt) {
            *(uint4*)&Av[cur ^ 1][tid * 8]        = ra0;
            *(uint4*)&Av[cur ^ 1][2048 + tid * 8] = ra1;
            *(uint4*)&Bv[cur ^ 1][tid * 8]        = rb0;
            *(uint4*)&Bv[cur ^ 1][2048 + tid * 8] = rb1;
        }
#endif
        __syncthreads();
        cur ^= 1;
    }

    // epilogue: scale by 1/l~(b, j) then atomic-accumulate
    float il[4];
#pragma unroll
    for (int jf = 0; jf < 4; ++jf) {
        int jg = jbase + wj * 64 + jf * 16 + lr;
        il[jf] = (jg < HWDIM) ? 1.0f / lws[b * HWDIM + jg] : 0.f;
    }
#pragma unroll
    for (int cf = 0; cf < 4; ++cf)
#pragma unroll
        for (int jf = 0; jf < 4; ++jf) {
            int jg = jbase + wj * 64 + jf * 16 + lr;
            if (jg < HWDIM) {
                int c = cbase + wc * 64 + cf * 16 + 4 * g;
                float* op = out + ((size_t)n * CVAL + c) * HWDIM + jg;
#pragma unroll
                for (int r4i = 0; r4i < 4; ++r4i)
                    atomicAdd(op + (size_t)r4i * HWDIM, acc[cf][jf][r4i] * il[jf]);
            }
        }
}

extern "C" void kernel_launch(void* const* d_in, const int* in_sizes, int n_in,
                              void* d_out, int out_size, void* d_ws, size_t ws_size,
                              hipStream_t stream) {
    (void)in_sizes; (void)n_in;
    const float* mk   = (const float*)d_in[0];   // mem_keys   [4,64,12960]
    const float* mv   = (const float*)d_in[1];   // mem_values [8,512,12960]
    const float* qkp  = (const float*)d_in[2];   // qk         [4,64,1620]
    const int*   bmap = (const int*)d_in[3];     // broadcast_map [8]
    float* out = (float*)d_out;

    // ws layout: k8l | mbnd | lws | mvb | kbt | Pws
    float* k8l  = (float*)d_ws;                           // NB*THW
    float* mbnd = k8l + NB * THW;                         // NB*HWDIM
    float* lws  = mbnd + NB * HWDIM;                      // NB*HWDIM
    unsigned short* mvb = (unsigned short*)(lws + NB * HWDIM);
    unsigned short* kbt = mvb + (size_t)NOBJ * CVAL * THW;
    unsigned short* Pws = kbt + (size_t)NB * THW * CKDIM;

    size_t base = ((size_t)NB * THW + 2 * (size_t)NB * HWDIM) * 4;
    size_t mvbB = (size_t)NOBJ * CVAL * THW * 2;
    size_t kbtB = (size_t)NB * THW * CKDIM * 2;
    size_t need_P4 = base + mvbB + kbtB + (size_t)4 * HWDIM * THW * 2;
    bool use_P4 = (ws_size >= need_P4);

    hipMemsetAsync(d_out, 0, (size_t)out_size * sizeof(float), stream);
    hipMemsetAsync(lws, 0, (size_t)NB * HWDIM * sizeof(float), stream);

    stcn_ktr_kernel<<<dim3((THW + 63) / 64, NB), 512, 0, stream>>>(mk, kbt, k8l);
    {
        size_t nthreads = (size_t)NOBJ * CVAL * THW / 8;
        stcn_vcvt_kernel<<<(unsigned)((nthreads + 255) / 256), 256, 0, stream>>>(mv, mvb);
    }
    stcn_qbound_kernel<<<dim3((HWDIM + 255) / 256, NB), 256, 0, stream>>>(qkp, mbnd);

    if (use_P4) {
        // one P pass for all 4 batches + one big GEMM
        stcn_pwrite_kernel<<<dim3(NJT * PCH, NB), 512, 0, stream>>>(
            kbt, qkp, k8l, mbnd, lws, Pws, 0);
        stcn_gemm3_kernel<true><<<dim3(1664), 256, 0, stream>>>(
            mvb, Pws, lws, bmap, out, 0);
    } else {
        // phased: P for b in {0,1} then {2,3}; inactive objects early-exit in GEMM
        for (int p = 0; p < 2; ++p) {
            stcn_pwrite_kernel<<<dim3(NJT * PCH, 2), 512, 0, stream>>>(
                kbt, qkp, k8l, mbnd, lws, Pws, 2 * p);
            stcn_gemm3_kernel<false><<<dim3(104, NOBJ), 256, 0, stream>>>(
                mvb, Pws, lws, bmap, out, p);
        }
    }
}

// Round 17
// 486.379 us; speedup vs baseline: 1.2205x; 1.0591x over previous
//
#include <hip/hip_runtime.h>
#include <hip/hip_bf16.h>

// STCN read_memory: affinity softmax over THW + value readout.
// Single-S-pass: P~ = exp2(L - Mbound(j)), l~(j) = sum_t P~; out = (sum P~ V)/l~.
// Mbound = |q|^2/8*log2e >= L exactly (2aq - a^2 = q^2 - |q-a|^2).
#define CKDIM 64
#define THW   12960     // 8*30*54
#define HWDIM 1620      // 30*54
#define NOBJ  8
#define CVAL  512
#define NB    4
#define NSTEP 405       // THW / 32
#define NJT   13        // ceil(1620/128)
#define PCH   16        // P-write K-chunks (R12-proven)
#define S2F   0.3606737602222409f   // 0.25 * log2(e)

#if defined(__has_builtin)
#if __has_builtin(__builtin_amdgcn_global_load_lds)
#define HAVE_GLL 1
#endif
#endif

using bf16x8 = __attribute__((ext_vector_type(8))) short;
using f32x4  = __attribute__((ext_vector_type(4))) float;

__device__ __forceinline__ unsigned cvtpk(float lo, float hi) {
    unsigned r;
    asm("v_cvt_pk_bf16_f32 %0, %1, %2" : "=v"(r) : "v"(lo), "v"(hi));
    return r;
}
__device__ __forceinline__ unsigned short bf_rne(float x) {
    unsigned u = __float_as_uint(x);
    u += 0x7FFFu + ((u >> 16) & 1u);
    return (unsigned short)(u >> 16);
}
__device__ __forceinline__ float fexp2(float x) {
#if __has_builtin(__builtin_amdgcn_exp2f)
    return __builtin_amdgcn_exp2f(x);
#else
    return __expf(x * 0.69314718055994531f);
#endif
}
#ifdef HAVE_GLL
__device__ __forceinline__ void gload16(const void* g, void* l) {
    __builtin_amdgcn_global_load_lds(
        (const __attribute__((address_space(1))) unsigned int*)g,
        (__attribute__((address_space(3))) unsigned int*)l, 16, 0, 0);
}
#endif

// K [b][c][t] f32 -> kbt [b][t][c] bf16 (RNE), fused k8l = |k|^2/8*log2e
__global__ __launch_bounds__(512)
void stcn_ktr_kernel(const float* __restrict__ mk, unsigned short* __restrict__ kbt,
                     float* __restrict__ k8l) {
    __shared__ unsigned short L[64][72];
    __shared__ float S[64][8];
    const int tid = threadIdx.x, b = blockIdx.y, t0 = blockIdx.x * 64;
    const int tt = tid & 63;
    float a2 = 0.f;
#pragma unroll
    for (int it = 0; it < 8; ++it) {
        int idx = tid + 512 * it;
        int c = idx >> 6;
        int t = t0 + tt;
        float v = (t < THW) ? mk[((size_t)b * CKDIM + c) * THW + t] : 0.f;
        L[tt][c] = bf_rne(v);
        a2 = fmaf(v, v, a2);
    }
    S[tt][tid >> 6] = a2;
    __syncthreads();
    if (tid < 64) {
        float s = 0.f;
#pragma unroll
        for (int q = 0; q < 8; ++q) s += S[tid][q];
        int t = t0 + tid;
        if (t < THW) k8l[b * THW + t] = s * (0.125f * 1.44269504088896341f);
    }
    {
        int tr = tid >> 3, cq = tid & 7;
        int t = t0 + tr;
        if (t < THW) {
            uint4 o = *(const uint4*)&L[tr][8 * cq];
            *(uint4*)(kbt + ((size_t)b * THW + t) * CKDIM + 8 * cq) = o;
        }
    }
}

// V f32 -> bf16 (RNE)
__global__ void stcn_vcvt_kernel(const float* __restrict__ mv, unsigned short* __restrict__ mvb) {
    size_t i = ((size_t)blockIdx.x * 256 + threadIdx.x) * 8;
    if (i >= (size_t)NOBJ * CVAL * THW) return;
    float4 v0 = *(const float4*)(mv + i);
    float4 v1 = *(const float4*)(mv + i + 4);
    uint4 o;
    o.x = cvtpk(v0.x, v0.y); o.y = cvtpk(v0.z, v0.w);
    o.z = cvtpk(v1.x, v1.y); o.w = cvtpk(v1.z, v1.w);
    *(uint4*)(mvb + i) = o;
}

// Mbound[b][j] = (sum_c q^2)/8 * log2e (exact upper bound on log2-logits)
__global__ void stcn_qbound_kernel(const float* __restrict__ qk, float* __restrict__ mbnd) {
    int j = blockIdx.x * 256 + threadIdx.x;
    if (j >= HWDIM) return;
    int b = blockIdx.y;
    const float* p = qk + (size_t)b * CKDIM * HWDIM + j;
    float s = 0.f;
#pragma unroll
    for (int c = 0; c < CKDIM; ++c) { float v = p[(size_t)c * HWDIM]; s = fmaf(v, v, s); }
    mbnd[b * HWDIM + j] = s * (0.125f * 1.44269504088896341f);
}

// ---------------- single-pass P-write: P~ (bf16) -> Pws[slot][j][THW], l~ atomics ----------------
__global__ __launch_bounds__(512)
void stcn_pwrite_kernel(const unsigned short* __restrict__ kbt,
                        const float* __restrict__ qk, const float* __restrict__ k8l,
                        const float* __restrict__ mbnd, float* __restrict__ lws,
                        unsigned short* __restrict__ Pws, int bbase)
{
    __shared__ __align__(16) unsigned char smem[36864];
    unsigned short* KtP  = (unsigned short*)smem;
    float*          k8tP = (float*)(smem + 9216);
    unsigned short* PtP  = (unsigned short*)(smem + 9472);
    unsigned short* QtP  = (unsigned short*)smem;

    const int tid  = threadIdx.x;
    const int w    = tid >> 6;
    const int lane = tid & 63;
    const int g    = lane >> 4;
    const int lr   = lane & 15;

    const int bb = blockIdx.y;
    const int b  = bbase + bb;
    const int jt = blockIdx.x / PCH, kc = blockIdx.x % PCH;
    const int jbase = jt * 128;

#pragma unroll
    for (int it = 0; it < 8; ++it) {
        int idx = tid + 512 * it;
        int j = idx & 127, cp = idx >> 7;
        int jg = jbase + j;
        float q0 = 0.f, q1 = 0.f;
        if (jg < HWDIM) {
            const float* qp = qk + ((size_t)b * CKDIM + 2 * cp) * HWDIM + jg;
            q0 = qp[0]; q1 = qp[HWDIM];
        }
        unsigned wh = cvtpk(q0, q1);
        float r0 = q0 - __uint_as_float(wh << 16);
        float r1 = q1 - __uint_as_float(wh & 0xFFFF0000u);
        *(unsigned*)&QtP[(0 * 128 + j) * 72 + 2 * cp] = wh;
        *(unsigned*)&QtP[(1 * 128 + j) * 72 + 2 * cp] = cvtpk(r0, r1);
    }
    __syncthreads();
    bf16x8 bqh[2], bql[2];
#pragma unroll
    for (int s = 0; s < 2; ++s) {
        bqh[s] = *(const bf16x8*)&QtP[(0 * 128 + w * 16 + lr) * 72 + 32 * s + 8 * g];
        bql[s] = *(const bf16x8*)&QtP[(1 * 128 + w * 16 + lr) * 72 + 32 * s + 8 * g];
    }
    __syncthreads();   // Qt dead

    const int s0 = (NSTEP * kc) / PCH, s1 = (NSTEP * (kc + 1)) / PCH;

    const int jgq = jbase + w * 16 + lr;
    const float mv_j = (jgq < HWDIM) ? mbnd[b * HWDIM + jgq] : 0.f;
    float lsum = 0.f;

    {
        int tt = tid >> 4, cq = tid & 15;
        uint2 k16 = *(const uint2*)(kbt + ((size_t)b * THW + s0 * 32 + tt) * CKDIM + 4 * cq);
        *(uint2*)&KtP[tt * 72 + 4 * cq] = k16;
        if (tid < 32) k8tP[tid] = k8l[b * THW + s0 * 32 + tid];
    }
    __syncthreads();

    f32x4 zz = {0.f, 0.f, 0.f, 0.f};
    int cur = 0;
    for (int st = s0; st < s1; ++st) {
        const int t0 = st * 32;
        const bool nxt = (st + 1 < s1);
        uint2 k16;
        float k8next = 0.f;
        const int tt = tid >> 4, cq = tid & 15;
        if (nxt) {
            k16 = *(const uint2*)(kbt + ((size_t)b * THW + (st + 1) * 32 + tt) * CKDIM + 4 * cq);
            if (tid < 32) k8next = k8l[b * THW + (st + 1) * 32 + tid];
        }
        bf16x8 ak0[2], ak1[2];
#pragma unroll
        for (int s = 0; s < 2; ++s) {
            ak0[s] = *(const bf16x8*)&KtP[(cur * 32 + lr) * 72 + 32 * s + 8 * g];
            ak1[s] = *(const bf16x8*)&KtP[(cur * 32 + 16 + lr) * 72 + 32 * s + 8 * g];
        }
        f32x4 k80 = *(const f32x4*)&k8tP[cur * 32 + 4 * g];
        f32x4 k81 = *(const f32x4*)&k8tP[cur * 32 + 16 + 4 * g];
        f32x4 ab0 = zz, ab1 = zz;
#pragma unroll
        for (int s = 0; s < 2; ++s) {
            ab0 = __builtin_amdgcn_mfma_f32_16x16x32_bf16(ak0[s], bqh[s], ab0, 0, 0, 0);
            ab0 = __builtin_amdgcn_mfma_f32_16x16x32_bf16(ak0[s], bql[s], ab0, 0, 0, 0);
            ab1 = __builtin_amdgcn_mfma_f32_16x16x32_bf16(ak1[s], bqh[s], ab1, 0, 0, 0);
            ab1 = __builtin_amdgcn_mfma_f32_16x16x32_bf16(ak1[s], bql[s], ab1, 0, 0, 0);
        }
        if (nxt) {
            *(uint2*)&KtP[((cur ^ 1) * 32 + tt) * 72 + 4 * cq] = k16;
            if (tid < 32) k8tP[(cur ^ 1) * 32 + tid] = k8next;
        }
        float p0[4], p1[4];
#pragma unroll
        for (int r = 0; r < 4; ++r) {
            p0[r] = fexp2(fmaf(ab0[r], S2F, -k80[r]) - mv_j);
            p1[r] = fexp2(fmaf(ab1[r], S2F, -k81[r]) - mv_j);
        }
        lsum += (p0[0] + p0[1] + p0[2] + p0[3]) + (p1[0] + p1[1] + p1[2] + p1[3]);
        __syncthreads();
        {
            int jl = w * 16 + lr;
            *(uint2*)&PtP[jl * 56 + 4 * g]      = make_uint2(cvtpk(p0[0], p0[1]), cvtpk(p0[2], p0[3]));
            *(uint2*)&PtP[jl * 56 + 16 + 4 * g] = make_uint2(cvtpk(p1[0], p1[1]), cvtpk(p1[2], p1[3]));
        }
        __syncthreads();
        {
            int jr = tid >> 2, qq = tid & 3;
            int jg = jbase + jr;
            if (jg < HWDIM)
                *(uint4*)(Pws + ((size_t)bb * HWDIM + jg) * THW + t0 + qq * 8) =
                    *(const uint4*)&PtP[jr * 56 + qq * 8];
        }
        cur ^= 1;
    }

    lsum += __shfl_xor(lsum, 16, 64);
    lsum += __shfl_xor(lsum, 32, 64);
    if (g == 0 && jgq < HWDIM)
        atomicAdd(&lws[b * HWDIM + jgq], lsum);
}

// ---------------- GEMM (proven): out[n][c][j] += (sum_t V P~) / l~(b,j) ----------------
// 128c x 128j tile, 4 waves of 64x64, BK=32, global_load_lds dbuf, slot-XOR swizzle.
// FULLP: 1-D grid 832 = 8n x 4cm x 2ks x 13jn; XCD-bijective (one n per XCD),
// jn INNERMOST (13 consecutive blocks share an L2-resident V half-slab);
// KSPLIT=2 halves the split-K atomic write traffic vs R16.
template <bool FULLP>
__global__ __launch_bounds__(256, 4)
void stcn_gemm3_kernel(const unsigned short* __restrict__ mvb,
                       const unsigned short* __restrict__ Pws,
                       const float* __restrict__ lws,
                       const int* __restrict__ bmap, float* __restrict__ out, int phase)
{
    __shared__ __align__(16) unsigned short Av[2][128 * 32];
    __shared__ __align__(16) unsigned short Bv[2][128 * 32];

    int n, cm, jn, ks, ksplit, bslot;
    if constexpr (FULLP) {
        int wg  = blockIdx.x;                      // 832
        int vid = (wg & 7) * 104 + (wg >> 3);      // bijective: each XCD owns one n
        n = vid / 104;
        int r  = vid % 104;
        cm = r / 26;
        int r2 = r % 26;
        ks = r2 / 13;                              // jn innermost: 13 consecutive blocks
        jn = r2 % 13;                              //   share V half-slab (n, cm, ks) in L2
        ksplit = 2;
    } else {
        n = blockIdx.y;
        const int x = blockIdx.x;                  // 2ks x 13jn x 4cm = 104
        ks = x & 1;
        const int rest = x >> 1;
        jn = rest % NJT;
        cm = rest / NJT;
        ksplit = 2;
    }
    const int b = bmap[n];
    if constexpr (FULLP) { bslot = b; }
    else { if ((b >> 1) != phase) return; bslot = b & 1; }

    const int jbase = jn * 128, cbase = cm * 128;

    const int tid = threadIdx.x;          // 256
    const int w = tid >> 6, lane = tid & 63, g = lane >> 4, lr = lane & 15;
    const int wc = w >> 1, wj = w & 1;    // 2x2 wave grid, 64x64 per wave

    const int srow = tid >> 2;
    const int tsw  = (((tid & 3) ^ ((tid >> 3) & 3)) << 3);   // pre-swizzled source t-offset
    const int gs8  = ((g ^ ((lr >> 1) & 3)) << 3);            // read-side swizzle

    const int s0 = (NSTEP * ks) / ksplit, s1 = (NSTEP * (ks + 1)) / ksplit;

    const unsigned short* abase = mvb + ((size_t)n * CVAL + cbase) * THW;
    const unsigned short* bbase = Pws + (size_t)bslot * HWDIM * THW;
    int jr0 = jbase + srow;       if (jr0 >= HWDIM) jr0 = 0;
    int jr1 = jbase + 64 + srow;  if (jr1 >= HWDIM) jr1 = 0;
    const unsigned short* ga0 = abase + (size_t)(srow) * THW + tsw;
    const unsigned short* ga1 = abase + (size_t)(64 + srow) * THW + tsw;
    const unsigned short* gb0 = bbase + (size_t)jr0 * THW + tsw;
    const unsigned short* gb1 = bbase + (size_t)jr1 * THW + tsw;

    f32x4 zz = {0.f, 0.f, 0.f, 0.f};
    f32x4 acc[4][4];
#pragma unroll
    for (int i = 0; i < 4; ++i)
#pragma unroll
        for (int j = 0; j < 4; ++j) acc[i][j] = zz;

#ifdef HAVE_GLL
    auto stage = [&](int buf, int st) {
        const int t0 = st * 32;
        gload16(ga0 + t0, &Av[buf][0    + w * 512]);
        gload16(ga1 + t0, &Av[buf][2048 + w * 512]);
        gload16(gb0 + t0, &Bv[buf][0    + w * 512]);
        gload16(gb1 + t0, &Bv[buf][2048 + w * 512]);
    };
    stage(0, s0);
#else
    {
        const int t0 = s0 * 32;
        *(uint4*)&Av[0][tid * 8]        = *(const uint4*)(ga0 + t0);
        *(uint4*)&Av[0][2048 + tid * 8] = *(const uint4*)(ga1 + t0);
        *(uint4*)&Bv[0][tid * 8]        = *(const uint4*)(gb0 + t0);
        *(uint4*)&Bv[0][2048 + tid * 8] = *(const uint4*)(gb1 + t0);
    }
#endif
    __syncthreads();

    int cur = 0;
    for (int st = s0; st < s1; ++st) {
        const bool nxt = (st + 1 < s1);
#ifdef HAVE_GLL
        if (nxt) stage(cur ^ 1, st + 1);
#else
        uint4 ra0, ra1, rb0, rb1;
        if (nxt) {
            const int t0 = (st + 1) * 32;
            ra0 = *(const uint4*)(ga0 + t0);
            ra1 = *(const uint4*)(ga1 + t0);
            rb0 = *(const uint4*)(gb0 + t0);
            rb1 = *(const uint4*)(gb1 + t0);
        }
#endif
        bf16x8 av[4], bp[4];
#pragma unroll
        for (int cf = 0; cf < 4; ++cf)
            av[cf] = *(const bf16x8*)&Av[cur][(wc * 64 + cf * 16 + lr) * 32 + gs8];
#pragma unroll
        for (int jf = 0; jf < 4; ++jf)
            bp[jf] = *(const bf16x8*)&Bv[cur][(wj * 64 + jf * 16 + lr) * 32 + gs8];
#pragma unroll
        for (int cf = 0; cf < 4; ++cf)
#pragma unroll
            for (int jf = 0; jf < 4; ++jf)
                acc[cf][jf] = __builtin_amdgcn_mfma_f32_16x16x32_bf16(av[cf], bp[jf], acc[cf][jf], 0, 0, 0);
#ifndef HAVE_GLL
        if (nxt) {
            *(uint4*)&Av[cur ^ 1][tid * 8]        = ra0;
            *(uint4*)&Av[cur ^ 1][2048 + tid * 8] = ra1;
            *(uint4*)&Bv[cur ^ 1][tid * 8]        = rb0;
            *(uint4*)&Bv[cur ^ 1][2048 + tid * 8] = rb1;
        }
#endif
        __syncthreads();
        cur ^= 1;
    }

    // epilogue: scale by 1/l~(b, j) then atomic-accumulate
    float il[4];
#pragma unroll
    for (int jf = 0; jf < 4; ++jf) {
        int jg = jbase + wj * 64 + jf * 16 + lr;
        il[jf] = (jg < HWDIM) ? 1.0f / lws[b * HWDIM + jg] : 0.f;
    }
#pragma unroll
    for (int cf = 0; cf < 4; ++cf)
#pragma unroll
        for (int jf = 0; jf < 4; ++jf) {
            int jg = jbase + wj * 64 + jf * 16 + lr;
            if (jg < HWDIM) {
                int c = cbase + wc * 64 + cf * 16 + 4 * g;
                float* op = out + ((size_t)n * CVAL + c) * HWDIM + jg;
#pragma unroll
                for (int r4i = 0; r4i < 4; ++r4i)
                    atomicAdd(op + (size_t)r4i * HWDIM, acc[cf][jf][r4i] * il[jf]);
            }
        }
}

extern "C" void kernel_launch(void* const* d_in, const int* in_sizes, int n_in,
                              void* d_out, int out_size, void* d_ws, size_t ws_size,
                              hipStream_t stream) {
    (void)in_sizes; (void)n_in;
    const float* mk   = (const float*)d_in[0];   // mem_keys   [4,64,12960]
    const float* mv   = (const float*)d_in[1];   // mem_values [8,512,12960]
    const float* qkp  = (const float*)d_in[2];   // qk         [4,64,1620]
    const int*   bmap = (const int*)d_in[3];     // broadcast_map [8]
    float* out = (float*)d_out;

    // ws layout: k8l | mbnd | lws | mvb | kbt | Pws
    float* k8l  = (float*)d_ws;                           // NB*THW
    float* mbnd = k8l + NB * THW;                         // NB*HWDIM
    float* lws  = mbnd + NB * HWDIM;                      // NB*HWDIM
    unsigned short* mvb = (unsigned short*)(lws + NB * HWDIM);
    unsigned short* kbt = mvb + (size_t)NOBJ * CVAL * THW;
    unsigned short* Pws = kbt + (size_t)NB * THW * CKDIM;

    size_t base = ((size_t)NB * THW + 2 * (size_t)NB * HWDIM) * 4;
    size_t mvbB = (size_t)NOBJ * CVAL * THW * 2;
    size_t kbtB = (size_t)NB * THW * CKDIM * 2;
    size_t need_P4 = base + mvbB + kbtB + (size_t)4 * HWDIM * THW * 2;
    bool use_P4 = (ws_size >= need_P4);

    hipMemsetAsync(d_out, 0, (size_t)out_size * sizeof(float), stream);
    hipMemsetAsync(lws, 0, (size_t)NB * HWDIM * sizeof(float), stream);

    stcn_ktr_kernel<<<dim3((THW + 63) / 64, NB), 512, 0, stream>>>(mk, kbt, k8l);
    {
        size_t nthreads = (size_t)NOBJ * CVAL * THW / 8;
        stcn_vcvt_kernel<<<(unsigned)((nthreads + 255) / 256), 256, 0, stream>>>(mv, mvb);
    }
    stcn_qbound_kernel<<<dim3((HWDIM + 255) / 256, NB), 256, 0, stream>>>(qkp, mbnd);

    if (use_P4) {
        // one P pass for all 4 batches + one big GEMM
        stcn_pwrite_kernel<<<dim3(NJT * PCH, NB), 512, 0, stream>>>(
            kbt, qkp, k8l, mbnd, lws, Pws, 0);
        stcn_gemm3_kernel<true><<<dim3(832), 256, 0, stream>>>(
            mvb, Pws, lws, bmap, out, 0);
    } else {
        // phased: P for b in {0,1} then {2,3}; inactive objects early-exit in GEMM
        for (int p = 0; p < 2; ++p) {
            stcn_pwrite_kernel<<<dim3(NJT * PCH, 2), 512, 0, stream>>>(
                kbt, qkp, k8l, mbnd, lws, Pws, 2 * p);
            stcn_gemm3_kernel<false><<<dim3(104, NOBJ), 256, 0, stream>>>(
                mvb, Pws, lws, bmap, out, p);
        }
    }
}